// Round 1
// baseline (485.049 us; speedup 1.0000x reference)
//
#include <hip/hip_runtime.h>
#include <stdint.h>

#define RMS_EPS 1.1920929e-07f
#define EPS_LIN 1e-6f

typedef __attribute__((ext_vector_type(8))) short bf16x8;
typedef __attribute__((ext_vector_type(4))) float f32x4;

__device__ __forceinline__ unsigned short f2bf(float f) {
  union { float f; unsigned int u; } v; v.f = f;
  unsigned int r = v.u + 0x7fffu + ((v.u >> 16) & 1u);
  return (unsigned short)(r >> 16);
}
__device__ __forceinline__ float bf2f(unsigned short s) {
  union { unsigned int u; float f; } v; v.u = ((unsigned int)s) << 16;
  return v.f;
}

// ---------------- fused init: f32->bf16 x3 + rope table + vkbuf zero ----------------
// block partition: [0,16384) x | [16384,19456) Wqkv | [19456,20480) Wout |
//                  [20480,20992) rope | [20992,21252) zero vkbuf
__global__ __launch_bounds__(256) void k_init(
    const float* __restrict__ x, const float* __restrict__ Wqkv,
    const float* __restrict__ Wout,
    unsigned short* __restrict__ xb, unsigned short* __restrict__ wqkvb,
    unsigned short* __restrict__ woutb,
    float* __restrict__ cosT, float* __restrict__ sinT,
    float* __restrict__ vkbuf) {
  const int blk = blockIdx.x;
  const int t = threadIdx.x;
  if (blk < 20480) {
    const float* src;
    unsigned short* dst;
    int base;
    if (blk < 16384) { src = x; dst = xb; base = blk; }
    else if (blk < 19456) { src = Wqkv; dst = wqkvb; base = blk - 16384; }
    else { src = Wout; dst = woutb; base = blk - 19456; }
    int i = (base * 256 + t) * 4;
    float4 v = *reinterpret_cast<const float4*>(src + i);
    ushort4 o = { f2bf(v.x), f2bf(v.y), f2bf(v.z), f2bf(v.w) };
    *reinterpret_cast<ushort4*>(dst + i) = o;
  } else if (blk < 20992) {
    int idx = (blk - 20480) * 256 + t;
    int l = idx >> 5, i = idx & 31;
    float inv_freq = expf(-((float)(2 * i) / 64.0f) * logf(10000.0f));
    float ang = (float)l * inv_freq;
    cosT[idx] = cosf(ang);
    sinT[idx] = sinf(ang);
  } else {
    int i = ((blk - 20992) * 256 + t) * 4;
    if (i < 64 * 65 * 64) {
      float4 z = { 0.f, 0.f, 0.f, 0.f };
      *reinterpret_cast<float4*>(vkbuf + i) = z;
    }
  }
}

// ---------------- async global->LDS 16B stage ----------------
__device__ __forceinline__ void stage16(const unsigned short* g, unsigned short* lds_base,
                                        int lane) {
#if __has_builtin(__builtin_amdgcn_global_load_lds)
  __builtin_amdgcn_global_load_lds(
      (const __attribute__((address_space(1))) unsigned int*)g,
      (__attribute__((address_space(3))) unsigned int*)lds_base, 16, 0, 0);
#else
  *reinterpret_cast<uint4*>(lds_base + lane * 8) = *reinterpret_cast<const uint4*>(g);
#endif
}

// ---------------- bf16 GEMM C = A(MxK) * B(NxK)^T + bias ----------------
// BK=64, XOR-swizzled LDS (R4: conflicts=0, 918 TF). Unchanged this round.
__global__ __launch_bounds__(256, 3) void k_gemm_bt(
    const unsigned short* __restrict__ A, const unsigned short* __restrict__ Bw,
    const float* __restrict__ bias, int M, int N, int K, int mode,
    unsigned short* __restrict__ qb, unsigned short* __restrict__ kb,
    unsigned short* __restrict__ vb, unsigned short* __restrict__ preb) {
  __shared__ unsigned short As[128 * 64];
  __shared__ unsigned short Bs[128 * 64];
  const int nt = N >> 7;
  const int bm = blockIdx.x / nt, bn = blockIdx.x % nt;
  const int m0 = bm << 7, n0 = bn << 7;
  const int t = threadIdx.x;
  const int wave = t >> 6, lane = t & 63;
  const int wr = wave >> 1, wc = wave & 1;
  const int quad = lane >> 4, m16 = lane & 15;

  const unsigned short* ApS[4];
  const unsigned short* BpS[4];
  unsigned short* AlS[4];
  unsigned short* BlS[4];
#pragma unroll
  for (int s = 0; s < 4; ++s) {
    int u = wave * 256 + s * 64 + lane;
    int row = u >> 3;
    int ku = (u & 7) ^ (row & 7);
    ApS[s] = A + (size_t)(m0 + row) * K + ku * 8;
    BpS[s] = Bw + (size_t)(n0 + row) * K + ku * 8;
    AlS[s] = As + (size_t)(wave * 256 + s * 64) * 8;
    BlS[s] = Bs + (size_t)(wave * 256 + s * 64) * 8;
  }

  int offA[4][2], offB[4][2];
#pragma unroll
  for (int i = 0; i < 4; ++i) {
    int rowA = wr * 64 + i * 16 + m16;
    int rowB = wc * 64 + i * 16 + m16;
#pragma unroll
    for (int ks = 0; ks < 2; ++ks) {
      int kuf = ks * 4 + quad;
      offA[i][ks] = (rowA * 8 + (kuf ^ (rowA & 7))) * 8;
      offB[i][ks] = (rowB * 8 + (kuf ^ (rowB & 7))) * 8;
    }
  }

  f32x4 acc[4][4] = {};

  for (int k0 = 0; k0 < K; k0 += 64) {
#pragma unroll
    for (int s = 0; s < 4; ++s) {
      stage16(ApS[s] + k0, AlS[s], lane);
      stage16(BpS[s] + k0, BlS[s], lane);
    }
    __syncthreads();
#pragma unroll
    for (int ks = 0; ks < 2; ++ks) {
      bf16x8 fa[4], fb[4];
#pragma unroll
      for (int i = 0; i < 4; ++i)
        fa[i] = *reinterpret_cast<const bf16x8*>(As + offA[i][ks]);
#pragma unroll
      for (int j = 0; j < 4; ++j)
        fb[j] = *reinterpret_cast<const bf16x8*>(Bs + offB[j][ks]);
#pragma unroll
      for (int i = 0; i < 4; ++i)
#pragma unroll
        for (int j = 0; j < 4; ++j)
          acc[i][j] = __builtin_amdgcn_mfma_f32_16x16x32_bf16(fa[i], fb[j], acc[i][j], 0, 0, 0);
    }
    __syncthreads();
  }

#pragma unroll
  for (int i = 0; i < 4; ++i) {
    int rbase = m0 + wr * 64 + i * 16 + quad * 4;
#pragma unroll
    for (int j = 0; j < 4; ++j) {
      int col = n0 + wc * 64 + j * 16 + m16;
      float bc = bias[col];
#pragma unroll
      for (int r = 0; r < 4; ++r) {
        int row = rbase + r;
        float val = acc[i][j][r] + bc;
        unsigned short bv = f2bf(val);
        if (mode == 0) {
          if (col < 1024) {
            qb[(size_t)row * 1024 + col] = bv;
          } else if (col < 2048) {
            kb[(size_t)row * 1024 + (col - 1024)] = bv;
          } else {
            int h = (col - 2048) >> 6, d = col & 63;
            int b = row >> 12, l = row & 4095;
            vb[(((size_t)(b * 16 + h)) * 4096 + l) * 64 + d] = bv;
          }
        } else {
          preb[(size_t)row * N + col] = bv;
        }
      }
    }
  }
}

// ---------------- q/k rmsnorm + rope + relu (wave-per-row, no barriers) ----------
__global__ __launch_bounds__(256) void k_qknorm(
    const unsigned short* __restrict__ qb, const unsigned short* __restrict__ kb,
    const float* __restrict__ gq, const float* __restrict__ gk,
    const float* __restrict__ cosT, const float* __restrict__ sinT,
    unsigned short* __restrict__ qfb, unsigned short* __restrict__ kfb) {
  const int wid = (blockIdx.x << 2) + (threadIdx.x >> 6);
  const int row = wid >> 1;
  const int which = wid & 1;
  const int lane = threadIdx.x & 63;
  const int l = row & 4095;
  const int b = row >> 12;
  const unsigned short* src = (which ? kb : qb) + (size_t)row * 1024;
  const float* g = which ? gk : gq;
  unsigned short* dstb = which ? kfb : qfb;

  float v[16];
  float ss = 0.f;
#pragma unroll
  for (int c = 0; c < 4; ++c) {
    int d = c * 256 + lane * 4;
    ushort4 u = *reinterpret_cast<const ushort4*>(src + d);
    float a0 = bf2f(u.x), a1 = bf2f(u.y), a2 = bf2f(u.z), a3 = bf2f(u.w);
    v[c * 4 + 0] = a0; v[c * 4 + 1] = a1; v[c * 4 + 2] = a2; v[c * 4 + 3] = a3;
    ss += a0 * a0 + a1 * a1 + a2 * a2 + a3 * a3;
  }
#pragma unroll
  for (int off = 1; off < 64; off <<= 1) ss += __shfl_xor(ss, off, 64);
  const float sc = rsqrtf(ss * (1.0f / 1024.0f) + RMS_EPS);

#pragma unroll
  for (int c = 0; c < 4; ++c) {
    int d = c * 256 + lane * 4;
    int i0 = (d & 63) >> 1;
    float c0 = cosT[l * 32 + i0], s0 = sinT[l * 32 + i0];
    float c1 = cosT[l * 32 + i0 + 1], s1 = sinT[l * 32 + i0 + 1];
    float x0 = v[c * 4 + 0] * sc * g[d];
    float x1 = v[c * 4 + 1] * sc * g[d + 1];
    float x2 = v[c * 4 + 2] * sc * g[d + 2];
    float x3 = v[c * 4 + 3] * sc * g[d + 3];
    float r0 = x0 * c0 - x1 * s0, r1 = x0 * s0 + x1 * c0;
    float r2 = x2 * c1 - x3 * s1, r3 = x2 * s1 + x3 * c1;
    ushort4 o = { f2bf(fmaxf(r0, 0.f)), f2bf(fmaxf(r1, 0.f)),
                  f2bf(fmaxf(r2, 0.f)), f2bf(fmaxf(r3, 0.f)) };
    int h = d >> 6;
    *reinterpret_cast<ushort4*>(dstb + (((size_t)(b * 16 + h)) * 4096 + l) * 64 + (d & 63)) = o;
  }
}

// ---------------- bf16x8 -> 2x float4 unpack helpers ----------------
__device__ __forceinline__ float4 lo4(uint4 u) {
  union { unsigned int v; float f; } a0, a1, b0, b1;
  a0.v = u.x << 16; a1.v = u.x & 0xffff0000u;
  b0.v = u.y << 16; b1.v = u.y & 0xffff0000u;
  float4 r = { a0.f, a1.f, b0.f, b1.f };
  return r;
}
__device__ __forceinline__ float4 hi4(uint4 u) {
  union { unsigned int v; float f; } a0, a1, b0, b1;
  a0.v = u.z << 16; a1.v = u.z & 0xffff0000u;
  b0.v = u.w << 16; b1.v = u.w & 0xffff0000u;
  float4 r = { a0.f, a1.f, b0.f, b1.f };
  return r;
}

// ---------------- vk[p][d] = sum_l vpad[l][p]*kf[l][d] (per bh) ----------------
// R6 rewrite: 8x8 register tile per lane (one wave covers full 64x64 output).
// LDS reads drop from 5 wave-instr / 16 outputs to 4 wave-instr / 64 outputs
// per lp (4x less LDS traffic; old version was LDS-issue-bound).
// Tiles are wave-private f32 [32][64] (64KB/block -> 2 blocks/CU).
// Block-level LDS reduction before global atomics (4.3M -> 2.2M atomics).
// Grid: 64 bh x 8 chunks = 512 blocks; wave w handles l-tiles chunk*16+w*4+it.
__global__ __launch_bounds__(256) void k_vk(const unsigned short* __restrict__ vb,
                                            const unsigned short* __restrict__ kfb,
                                            float* __restrict__ vk) {
  const int bh = blockIdx.x >> 3;
  const int chunk = blockIdx.x & 7;
  const int t = threadIdx.x;
  const int wv = t >> 6, lane = t & 63;
  const int p0 = (lane >> 3) << 3, d0 = (lane & 7) << 3;
  // [0,8192): v tiles (4 waves x 2048 f32 = 32x64); [8192,16384): k tiles
  __shared__ float sh[16384];
  float* vt = sh + wv * 2048;
  float* kt = sh + 8192 + wv * 2048;

  float acc[8][8] = {};
  float accD[8] = {};

  for (int it = 0; it < 4; ++it) {
    const int l0 = (chunk * 16 + wv * 4 + it) * 32;
    const size_t base = ((size_t)bh * 4096 + l0) * 64;
    // stage 32x64 bf16 -> f32, wave-local, coalesced 16B/lane
#pragma unroll
    for (int c = 0; c < 4; ++c) {
      const int e = c * 512 + lane * 8;
      uint4 uv = *reinterpret_cast<const uint4*>(vb + base + e);
      uint4 uk = *reinterpret_cast<const uint4*>(kfb + base + e);
      *reinterpret_cast<float4*>(vt + e) = lo4(uv);
      *reinterpret_cast<float4*>(vt + e + 4) = hi4(uv);
      *reinterpret_cast<float4*>(kt + e) = lo4(uk);
      *reinterpret_cast<float4*>(kt + e + 4) = hi4(uk);
    }
    __syncthreads();
#pragma unroll 2
    for (int lp = 0; lp < 32; ++lp) {
      const float* vr = vt + lp * 64 + p0;
      const float* kr = kt + lp * 64 + d0;
      float4 v0 = *reinterpret_cast<const float4*>(vr);
      float4 v1 = *reinterpret_cast<const float4*>(vr + 4);
      float4 k0 = *reinterpret_cast<const float4*>(kr);
      float4 k1 = *reinterpret_cast<const float4*>(kr + 4);
      float vv[8] = { v0.x, v0.y, v0.z, v0.w, v1.x, v1.y, v1.z, v1.w };
      float kk[8] = { k0.x, k0.y, k0.z, k0.w, k1.x, k1.y, k1.z, k1.w };
#pragma unroll
      for (int i = 0; i < 8; ++i)
#pragma unroll
        for (int j = 0; j < 8; ++j)
          acc[i][j] += vv[i] * kk[j];
#pragma unroll
      for (int j = 0; j < 8; ++j) accD[j] += kk[j];
    }
    __syncthreads();
  }

  // block reduce: wave w dumps its 64x64 partial into sh[w*4096 ..), then
  // each thread sums 16 outputs across the 4 waves and does one atomic each.
  float* reg = sh + wv * 4096;
#pragma unroll
  for (int i = 0; i < 8; ++i) {
    float4 lo = { acc[i][0], acc[i][1], acc[i][2], acc[i][3] };
    float4 hi = { acc[i][4], acc[i][5], acc[i][6], acc[i][7] };
    *reinterpret_cast<float4*>(reg + (p0 + i) * 64 + d0) = lo;
    *reinterpret_cast<float4*>(reg + (p0 + i) * 64 + d0 + 4) = hi;
  }
  __syncthreads();
  float* dst = vk + (size_t)bh * 65 * 64;
#pragma unroll
  for (int q = 0; q < 4; ++q) {
    const int o = t * 16 + q * 4;
    float4 s = *reinterpret_cast<const float4*>(sh + o);
#pragma unroll
    for (int w = 1; w < 4; ++w) {
      float4 r = *reinterpret_cast<const float4*>(sh + w * 4096 + o);
      s.x += r.x; s.y += r.y; s.z += r.z; s.w += r.w;
    }
    atomicAdd(dst + o + 0, s.x);
    atomicAdd(dst + o + 1, s.y);
    atomicAdd(dst + o + 2, s.z);
    atomicAdd(dst + o + 3, s.w);
  }
  // denominator row p=64: lanes 0..7 of each wave hold accD for d0..d0+7
  if (lane < 8) {
#pragma unroll
    for (int j = 0; j < 8; ++j) atomicAdd(dst + 64 * 64 + d0 + j, accD[j]);
  }
}

// ---------------- res = qf . vk^T ; attn = res/(den+eps) -> bf16 BLD ----------------
__global__ __launch_bounds__(256) void k_res(const unsigned short* __restrict__ qfb,
                                             const float* __restrict__ vk,
                                             unsigned short* __restrict__ attnb) {
  const int bh = blockIdx.x >> 5;
  const int lt = (blockIdx.x & 31) << 7;
  const int b = bh >> 4, h = bh & 15;
  const int t = threadIdx.x;
  const int wave = t >> 6, lane = t & 63;
  __shared__ unsigned short Aq[128 * 64];
  __shared__ unsigned short Bv[64 * 64];
  __shared__ float vkD[64];
  __shared__ float invden[128];

  const unsigned short* Ag = qfb + ((size_t)bh * 4096 + lt) * 64;
#pragma unroll
  for (int s = 0; s < 4; ++s)
    stage16(Ag + wave * 2048 + s * 512 + lane * 8, Aq + wave * 2048 + s * 512, lane);

  const float* vsrc = vk + (size_t)bh * 65 * 64;
  {
    int base = t * 16;
#pragma unroll
    for (int c = 0; c < 4; ++c) {
      float4 f = *reinterpret_cast<const float4*>(vsrc + base + c * 4);
      ushort4 o = { f2bf(f.x), f2bf(f.y), f2bf(f.z), f2bf(f.w) };
      *reinterpret_cast<ushort4*>(Bv + base + c * 4) = o;
    }
  }
  if (t < 64) vkD[t] = vsrc[64 * 64 + t];
  __syncthreads();

  f32x4 acc[2][4] = {};
  const int quad = lane >> 4, m16 = lane & 15;
#pragma unroll
  for (int step = 0; step < 2; ++step) {
    bf16x8 fa[2], fb[4];
#pragma unroll
    for (int i = 0; i < 2; ++i)
      fa[i] = *reinterpret_cast<const bf16x8*>(Aq + (wave * 32 + i * 16 + m16) * 64 +
                                               step * 32 + quad * 8);
#pragma unroll
    for (int j = 0; j < 4; ++j)
      fb[j] = *reinterpret_cast<const bf16x8*>(Bv + (j * 16 + m16) * 64 +
                                               step * 32 + quad * 8);
#pragma unroll
    for (int i = 0; i < 2; ++i)
#pragma unroll
      for (int j = 0; j < 4; ++j)
        acc[i][j] = __builtin_amdgcn_mfma_f32_16x16x32_bf16(fa[i], fb[j], acc[i][j], 0, 0, 0);
  }

  {
    const unsigned short* qr = Aq + (t >> 1) * 64 + (t & 1) * 32;
    const float* vd = vkD + (t & 1) * 32;
    float ds = 0.f;
#pragma unroll
    for (int c = 0; c < 4; ++c) {
      bf16x8 qv = *reinterpret_cast<const bf16x8*>(qr + c * 8);
#pragma unroll
      for (int j = 0; j < 8; ++j)
        ds += bf2f((unsigned short)qv[j]) * vd[c * 8 + j];
    }
    ds += __shfl_xor(ds, 1, 64);
    if ((t & 1) == 0) invden[t >> 1] = 1.0f / (ds + EPS_LIN);
  }
  __syncthreads();

#pragma unroll
  for (int i = 0; i < 2; ++i) {
#pragma unroll
    for (int r = 0; r < 4; ++r) {
      int row = wave * 32 + i * 16 + quad * 4 + r;
      float inv = invden[row];
      unsigned short* dst = attnb + ((size_t)(b * 4096 + lt + row)) * 1024 + h * 64;
#pragma unroll
      for (int j = 0; j < 4; ++j)
        dst[j * 16 + m16] = f2bf(acc[i][j][r] * inv);
    }
  }
}

// ---------------- final rmsnorm (wave-per-row, no barriers) ----------------
__global__ __launch_bounds__(256) void k_outnorm(const unsigned short* __restrict__ preb,
                                                 const float* __restrict__ gout,
                                                 float* __restrict__ out) {
  const int row = (blockIdx.x << 2) + (threadIdx.x >> 6);
  const int lane = threadIdx.x & 63;
  const unsigned short* src = preb + (size_t)row * 1024;
  float* drow = out + (size_t)row * 1024;
  float v[16];
  float ss = 0.f;
#pragma unroll
  for (int c = 0; c < 4; ++c) {
    int d = c * 256 + lane * 4;
    ushort4 u = *reinterpret_cast<const ushort4*>(src + d);
    float a0 = bf2f(u.x), a1 = bf2f(u.y), a2 = bf2f(u.z), a3 = bf2f(u.w);
    v[c * 4 + 0] = a0; v[c * 4 + 1] = a1; v[c * 4 + 2] = a2; v[c * 4 + 3] = a3;
    ss += a0 * a0 + a1 * a1 + a2 * a2 + a3 * a3;
  }
#pragma unroll
  for (int off = 1; off < 64; off <<= 1) ss += __shfl_xor(ss, off, 64);
  const float sc = rsqrtf(ss * (1.0f / 1024.0f) + RMS_EPS);
#pragma unroll
  for (int c = 0; c < 4; ++c) {
    int d = c * 256 + lane * 4;
    float4 o = { v[c * 4 + 0] * sc * gout[d], v[c * 4 + 1] * sc * gout[d + 1],
                 v[c * 4 + 2] * sc * gout[d + 2], v[c * 4 + 3] * sc * gout[d + 3] };
    *reinterpret_cast<float4*>(drow + d) = o;
  }
}

// ---------------- workspace layout (bytes) ----------------
#define OFF_XB     0ull
#define OFF_WQKVB  33554432ull
#define OFF_WOUTB  39845888ull
#define OFF_QB     41943040ull
#define OFF_KB     75497472ull
#define OFF_VB     109051904ull
#define OFF_QFB    142606336ull
#define OFF_KFB    176160768ull
#define OFF_VK     209715200ull
#define OFF_ATTNB  210780160ull
#define OFF_COST   244334592ull
#define OFF_SINT   244858880ull
#define WS_NEEDED  245383168ull
// preb (bf16, 32MB) aliases OFF_QB (qb dead by then)

extern "C" void kernel_launch(void* const* d_in, const int* in_sizes, int n_in,
                              void* d_out, int out_size, void* d_ws, size_t ws_size,
                              hipStream_t stream) {
  const float* x    = (const float*)d_in[0];
  const float* Wqkv = (const float*)d_in[1];
  const float* bqkv = (const float*)d_in[2];
  const float* gq   = (const float*)d_in[3];
  const float* gk   = (const float*)d_in[4];
  const float* Wout = (const float*)d_in[5];
  const float* bout = (const float*)d_in[6];
  const float* gout = (const float*)d_in[7];

  if (ws_size < WS_NEEDED) return;

  char* ws = (char*)d_ws;
  unsigned short* xb    = (unsigned short*)(ws + OFF_XB);
  unsigned short* wqkvb = (unsigned short*)(ws + OFF_WQKVB);
  unsigned short* woutb = (unsigned short*)(ws + OFF_WOUTB);
  unsigned short* qb    = (unsigned short*)(ws + OFF_QB);
  unsigned short* kb    = (unsigned short*)(ws + OFF_KB);
  unsigned short* vb    = (unsigned short*)(ws + OFF_VB);
  unsigned short* qfb   = (unsigned short*)(ws + OFF_QFB);
  unsigned short* kfb   = (unsigned short*)(ws + OFF_KFB);
  float*          vkbuf = (float*)(ws + OFF_VK);
  unsigned short* attnb = (unsigned short*)(ws + OFF_ATTNB);
  float*          cosT  = (float*)(ws + OFF_COST);
  float*          sinT  = (float*)(ws + OFF_SINT);
  unsigned short* preb  = (unsigned short*)(ws + OFF_QB);  // alias

  // fused init: conversions + rope table + vkbuf zero (1 launch)
  k_init<<<21252, 256, 0, stream>>>(x, Wqkv, Wout, xb, wqkvb, woutb, cosT, sinT, vkbuf);

  // QKV gemm: M=16384 N=3072 K=1024
  k_gemm_bt<<<128 * 24, 256, 0, stream>>>(xb, wqkvb, bqkv, 16384, 3072, 1024, 0,
                                          qb, kb, vb, nullptr);
  k_qknorm<<<8192, 256, 0, stream>>>(qb, kb, gq, gk, cosT, sinT, qfb, kfb);

  // R6: 64 bh x 8 chunks, 8x8 register tile, block-reduced atomics
  k_vk<<<512, 256, 0, stream>>>(vb, kfb, vkbuf);
  k_res<<<2048, 256, 0, stream>>>(qfb, vkbuf, attnb);

  // out gemm: M=16384 N=1024 K=1024 -> preb (bf16, aliases qb region)
  k_gemm_bt<<<128 * 8, 256, 0, stream>>>(attnb, woutb, bout, 16384, 1024, 1024, 1,
                                         nullptr, nullptr, nullptr, preb);
  k_outnorm<<<4096, 256, 0, stream>>>(preb, gout, (float*)d_out);
}

// Round 3
// 370.372 us; speedup vs baseline: 1.3096x; 1.3096x over previous
//
#include <hip/hip_runtime.h>
#include <stdint.h>

#define RMS_EPS 1.1920929e-07f
#define EPS_LIN 1e-6f

typedef __attribute__((ext_vector_type(8))) short bf16x8;
typedef __attribute__((ext_vector_type(4))) float f32x4;

__device__ __forceinline__ unsigned short f2bf(float f) {
  union { float f; unsigned int u; } v; v.f = f;
  unsigned int r = v.u + 0x7fffu + ((v.u >> 16) & 1u);
  return (unsigned short)(r >> 16);
}
__device__ __forceinline__ float bf2f(unsigned short s) {
  union { unsigned int u; float f; } v; v.u = ((unsigned int)s) << 16;
  return v.f;
}

// ---------------- fused init: f32->bf16 x3 + rope table + vkbuf zero ----------------
__global__ __launch_bounds__(256) void k_init(
    const float* __restrict__ x, const float* __restrict__ Wqkv,
    const float* __restrict__ Wout,
    unsigned short* __restrict__ xb, unsigned short* __restrict__ wqkvb,
    unsigned short* __restrict__ woutb,
    float* __restrict__ cosT, float* __restrict__ sinT,
    float* __restrict__ vkbuf) {
  const int blk = blockIdx.x;
  const int t = threadIdx.x;
  if (blk < 20480) {
    const float* src;
    unsigned short* dst;
    int base;
    if (blk < 16384) { src = x; dst = xb; base = blk; }
    else if (blk < 19456) { src = Wqkv; dst = wqkvb; base = blk - 16384; }
    else { src = Wout; dst = woutb; base = blk - 19456; }
    int i = (base * 256 + t) * 4;
    float4 v = *reinterpret_cast<const float4*>(src + i);
    ushort4 o = { f2bf(v.x), f2bf(v.y), f2bf(v.z), f2bf(v.w) };
    *reinterpret_cast<ushort4*>(dst + i) = o;
  } else if (blk < 20992) {
    int idx = (blk - 20480) * 256 + t;
    int l = idx >> 5, i = idx & 31;
    float inv_freq = expf(-((float)(2 * i) / 64.0f) * logf(10000.0f));
    float ang = (float)l * inv_freq;
    cosT[idx] = cosf(ang);
    sinT[idx] = sinf(ang);
  } else {
    int i = ((blk - 20992) * 256 + t) * 4;
    if (i < 64 * 65 * 64) {
      float4 z = { 0.f, 0.f, 0.f, 0.f };
      *reinterpret_cast<float4*>(vkbuf + i) = z;
    }
  }
}

// ---------------- async global->LDS 16B stage ----------------
__device__ __forceinline__ void stage16(const unsigned short* g, unsigned short* lds_base,
                                        int lane) {
#if __has_builtin(__builtin_amdgcn_global_load_lds)
  __builtin_amdgcn_global_load_lds(
      (const __attribute__((address_space(1))) unsigned int*)g,
      (__attribute__((address_space(3))) unsigned int*)lds_base, 16, 0, 0);
#else
  *reinterpret_cast<uint4*>(lds_base + lane * 8) = *reinterpret_cast<const uint4*>(g);
#endif
}

// ---------------- bf16 GEMM C = A(MxK) * B(NxK)^T + bias ----------------
// BK=64, XOR-swizzled LDS (918 TF). Unchanged this round.
__global__ __launch_bounds__(256, 3) void k_gemm_bt(
    const unsigned short* __restrict__ A, const unsigned short* __restrict__ Bw,
    const float* __restrict__ bias, int M, int N, int K, int mode,
    unsigned short* __restrict__ qb, unsigned short* __restrict__ kb,
    unsigned short* __restrict__ vb, unsigned short* __restrict__ preb) {
  __shared__ unsigned short As[128 * 64];
  __shared__ unsigned short Bs[128 * 64];
  const int nt = N >> 7;
  const int bm = blockIdx.x / nt, bn = blockIdx.x % nt;
  const int m0 = bm << 7, n0 = bn << 7;
  const int t = threadIdx.x;
  const int wave = t >> 6, lane = t & 63;
  const int wr = wave >> 1, wc = wave & 1;
  const int quad = lane >> 4, m16 = lane & 15;

  const unsigned short* ApS[4];
  const unsigned short* BpS[4];
  unsigned short* AlS[4];
  unsigned short* BlS[4];
#pragma unroll
  for (int s = 0; s < 4; ++s) {
    int u = wave * 256 + s * 64 + lane;
    int row = u >> 3;
    int ku = (u & 7) ^ (row & 7);
    ApS[s] = A + (size_t)(m0 + row) * K + ku * 8;
    BpS[s] = Bw + (size_t)(n0 + row) * K + ku * 8;
    AlS[s] = As + (size_t)(wave * 256 + s * 64) * 8;
    BlS[s] = Bs + (size_t)(wave * 256 + s * 64) * 8;
  }

  int offA[4][2], offB[4][2];
#pragma unroll
  for (int i = 0; i < 4; ++i) {
    int rowA = wr * 64 + i * 16 + m16;
    int rowB = wc * 64 + i * 16 + m16;
#pragma unroll
    for (int ks = 0; ks < 2; ++ks) {
      int kuf = ks * 4 + quad;
      offA[i][ks] = (rowA * 8 + (kuf ^ (rowA & 7))) * 8;
      offB[i][ks] = (rowB * 8 + (kuf ^ (rowB & 7))) * 8;
    }
  }

  f32x4 acc[4][4] = {};

  for (int k0 = 0; k0 < K; k0 += 64) {
#pragma unroll
    for (int s = 0; s < 4; ++s) {
      stage16(ApS[s] + k0, AlS[s], lane);
      stage16(BpS[s] + k0, BlS[s], lane);
    }
    __syncthreads();
#pragma unroll
    for (int ks = 0; ks < 2; ++ks) {
      bf16x8 fa[4], fb[4];
#pragma unroll
      for (int i = 0; i < 4; ++i)
        fa[i] = *reinterpret_cast<const bf16x8*>(As + offA[i][ks]);
#pragma unroll
      for (int j = 0; j < 4; ++j)
        fb[j] = *reinterpret_cast<const bf16x8*>(Bs + offB[j][ks]);
#pragma unroll
      for (int i = 0; i < 4; ++i)
#pragma unroll
        for (int j = 0; j < 4; ++j)
          acc[i][j] = __builtin_amdgcn_mfma_f32_16x16x32_bf16(fa[i], fb[j], acc[i][j], 0, 0, 0);
    }
    __syncthreads();
  }

#pragma unroll
  for (int i = 0; i < 4; ++i) {
    int rbase = m0 + wr * 64 + i * 16 + quad * 4;
#pragma unroll
    for (int j = 0; j < 4; ++j) {
      int col = n0 + wc * 64 + j * 16 + m16;
      float bc = bias[col];
#pragma unroll
      for (int r = 0; r < 4; ++r) {
        int row = rbase + r;
        float val = acc[i][j][r] + bc;
        unsigned short bv = f2bf(val);
        if (mode == 0) {
          if (col < 1024) {
            qb[(size_t)row * 1024 + col] = bv;
          } else if (col < 2048) {
            kb[(size_t)row * 1024 + (col - 1024)] = bv;
          } else {
            int h = (col - 2048) >> 6, d = col & 63;
            int b = row >> 12, l = row & 4095;
            vb[(((size_t)(b * 16 + h)) * 4096 + l) * 64 + d] = bv;
          }
        } else {
          preb[(size_t)row * N + col] = bv;
        }
      }
    }
  }
}

// ---------------- q/k rmsnorm + rope + relu (wave-per-row, no barriers) ----------
__global__ __launch_bounds__(256) void k_qknorm(
    const unsigned short* __restrict__ qb, const unsigned short* __restrict__ kb,
    const float* __restrict__ gq, const float* __restrict__ gk,
    const float* __restrict__ cosT, const float* __restrict__ sinT,
    unsigned short* __restrict__ qfb, unsigned short* __restrict__ kfb) {
  const int wid = (blockIdx.x << 2) + (threadIdx.x >> 6);
  const int row = wid >> 1;
  const int which = wid & 1;
  const int lane = threadIdx.x & 63;
  const int l = row & 4095;
  const int b = row >> 12;
  const unsigned short* src = (which ? kb : qb) + (size_t)row * 1024;
  const float* g = which ? gk : gq;
  unsigned short* dstb = which ? kfb : qfb;

  float v[16];
  float ss = 0.f;
#pragma unroll
  for (int c = 0; c < 4; ++c) {
    int d = c * 256 + lane * 4;
    ushort4 u = *reinterpret_cast<const ushort4*>(src + d);
    float a0 = bf2f(u.x), a1 = bf2f(u.y), a2 = bf2f(u.z), a3 = bf2f(u.w);
    v[c * 4 + 0] = a0; v[c * 4 + 1] = a1; v[c * 4 + 2] = a2; v[c * 4 + 3] = a3;
    ss += a0 * a0 + a1 * a1 + a2 * a2 + a3 * a3;
  }
#pragma unroll
  for (int off = 1; off < 64; off <<= 1) ss += __shfl_xor(ss, off, 64);
  const float sc = rsqrtf(ss * (1.0f / 1024.0f) + RMS_EPS);

#pragma unroll
  for (int c = 0; c < 4; ++c) {
    int d = c * 256 + lane * 4;
    int i0 = (d & 63) >> 1;
    float c0 = cosT[l * 32 + i0], s0 = sinT[l * 32 + i0];
    float c1 = cosT[l * 32 + i0 + 1], s1 = sinT[l * 32 + i0 + 1];
    float x0 = v[c * 4 + 0] * sc * g[d];
    float x1 = v[c * 4 + 1] * sc * g[d + 1];
    float x2 = v[c * 4 + 2] * sc * g[d + 2];
    float x3 = v[c * 4 + 3] * sc * g[d + 3];
    float r0 = x0 * c0 - x1 * s0, r1 = x0 * s0 + x1 * c0;
    float r2 = x2 * c1 - x3 * s1, r3 = x2 * s1 + x3 * c1;
    ushort4 o = { f2bf(fmaxf(r0, 0.f)), f2bf(fmaxf(r1, 0.f)),
                  f2bf(fmaxf(r2, 0.f)), f2bf(fmaxf(r3, 0.f)) };
    int h = d >> 6;
    *reinterpret_cast<ushort4*>(dstb + (((size_t)(b * 16 + h)) * 4096 + l) * 64 + (d & 63)) = o;
  }
}

// ---------------- vk[p][d] = sum_l vpad[l][p]*kf[l][d] (per bh) -- MFMA ----------
// R8: same structure as R7 (per-chunk partials, no atomics) but NO tr_read.
// Tiles stored TRANSPOSED in LDS: Vt[d][l], Kt[d][l], row stride 40 shorts
// (mult of 8 -> aligned ds_read_b128; +8 pad spreads banks). Staging: thread
// (wv,lane) owns d=lane, rows l=wv*8..wv*8+7: 8 coalesced scalar loads (lanes
// span 64 contiguous d = 128B/instr) + one ds_write_b128 down its LDS row.
// Fragments = 8 contiguous shorts = plain ds_read_b128 (k_gemm_bt idiom).
// Wave wv owns p-quarter wv: fa = Vt[wv*16+m16][quad*8+e]  (A[p][l])
//                            fb[j] = Kt[j*16+m16][quad*8+e] (B[l][d] col-frag)
// Output D: p = wv*16 + quad*4 + r, d = j*16 + m16 (m89 C/D layout).
__global__ __launch_bounds__(256) void k_vk(const unsigned short* __restrict__ vb,
                                            const unsigned short* __restrict__ kfb,
                                            float* __restrict__ part) {
  const int bh = blockIdx.x >> 4;
  const int chunk = blockIdx.x & 15;
  const int t = threadIdx.x;
  const int wv = t >> 6, lane = t & 63;
  const int quad = lane >> 4, m16 = lane & 15;

  __shared__ __align__(16) unsigned short Vt[64 * 40];
  __shared__ __align__(16) unsigned short Kt[64 * 40];
  __shared__ float dred[4][64];

  f32x4 acc[4] = {};
  float accD = 0.f;

  for (int tile = 0; tile < 8; ++tile) {
    // global rows l = chunk*256 + tile*32 + wv*8 + j, column d = lane
    const size_t rbase =
        ((size_t)bh * 4096 + chunk * 256 + tile * 32 + wv * 8) * 64 + lane;
    bf16x8 vv, kv;
#pragma unroll
    for (int j = 0; j < 8; ++j) {
      unsigned short ve = vb[rbase + j * 64];
      unsigned short ke = kfb[rbase + j * 64];
      vv[j] = (short)ve;
      kv[j] = (short)ke;
      accD += bf2f(ke);
    }
    *reinterpret_cast<bf16x8*>(Vt + lane * 40 + wv * 8) = vv;
    *reinterpret_cast<bf16x8*>(Kt + lane * 40 + wv * 8) = kv;
    __syncthreads();

    bf16x8 fa = *reinterpret_cast<const bf16x8*>(Vt + (wv * 16 + m16) * 40 + quad * 8);
#pragma unroll
    for (int j = 0; j < 4; ++j) {
      bf16x8 fb = *reinterpret_cast<const bf16x8*>(Kt + (j * 16 + m16) * 40 + quad * 8);
      acc[j] = __builtin_amdgcn_mfma_f32_16x16x32_bf16(fa, fb, acc[j], 0, 0, 0);
    }
    __syncthreads();
  }

  // per-chunk partial: p = wv*16 + quad*4 + r, d = j*16 + m16
  float* dst = part + ((size_t)chunk * 64 + bh) * 4160;
#pragma unroll
  for (int j = 0; j < 4; ++j)
#pragma unroll
    for (int r = 0; r < 4; ++r)
      dst[(wv * 16 + quad * 4 + r) * 64 + j * 16 + m16] = acc[j][r];

  // denominator row p=64: thread (wv,lane) holds sum over its rows for d=lane
  dred[wv][lane] = accD;
  __syncthreads();
  if (t < 64) dst[64 * 64 + t] = dred[0][t] + dred[1][t] + dred[2][t] + dred[3][t];
}

// ---------------- reduce 16 per-chunk partials -> vkbuf ----------------
__global__ __launch_bounds__(256) void k_vkred(const float* __restrict__ part,
                                               float* __restrict__ vk) {
  const int i = (blockIdx.x * 256 + threadIdx.x) * 4;  // 260*1024 == 266240 exact
  float4 s = *reinterpret_cast<const float4*>(part + i);
#pragma unroll
  for (int c = 1; c < 16; ++c) {
    float4 r = *reinterpret_cast<const float4*>(part + (size_t)c * 266240 + i);
    s.x += r.x; s.y += r.y; s.z += r.z; s.w += r.w;
  }
  *reinterpret_cast<float4*>(vk + i) = s;
}

// ---------------- res = qf . vk^T ; attn = res/(den+eps) -> bf16 BLD ----------------
__global__ __launch_bounds__(256) void k_res(const unsigned short* __restrict__ qfb,
                                             const float* __restrict__ vk,
                                             unsigned short* __restrict__ attnb) {
  const int bh = blockIdx.x >> 5;
  const int lt = (blockIdx.x & 31) << 7;
  const int b = bh >> 4, h = bh & 15;
  const int t = threadIdx.x;
  const int wave = t >> 6, lane = t & 63;
  __shared__ unsigned short Aq[128 * 64];
  __shared__ unsigned short Bv[64 * 64];
  __shared__ float vkD[64];
  __shared__ float invden[128];

  const unsigned short* Ag = qfb + ((size_t)bh * 4096 + lt) * 64;
#pragma unroll
  for (int s = 0; s < 4; ++s)
    stage16(Ag + wave * 2048 + s * 512 + lane * 8, Aq + wave * 2048 + s * 512, lane);

  const float* vsrc = vk + (size_t)bh * 65 * 64;
  {
    int base = t * 16;
#pragma unroll
    for (int c = 0; c < 4; ++c) {
      float4 f = *reinterpret_cast<const float4*>(vsrc + base + c * 4);
      ushort4 o = { f2bf(f.x), f2bf(f.y), f2bf(f.z), f2bf(f.w) };
      *reinterpret_cast<ushort4*>(Bv + base + c * 4) = o;
    }
  }
  if (t < 64) vkD[t] = vsrc[64 * 64 + t];
  __syncthreads();

  f32x4 acc[2][4] = {};
  const int quad = lane >> 4, m16 = lane & 15;
#pragma unroll
  for (int step = 0; step < 2; ++step) {
    bf16x8 fa[2], fb[4];
#pragma unroll
    for (int i = 0; i < 2; ++i)
      fa[i] = *reinterpret_cast<const bf16x8*>(Aq + (wave * 32 + i * 16 + m16) * 64 +
                                               step * 32 + quad * 8);
#pragma unroll
    for (int j = 0; j < 4; ++j)
      fb[j] = *reinterpret_cast<const bf16x8*>(Bv + (j * 16 + m16) * 64 +
                                               step * 32 + quad * 8);
#pragma unroll
    for (int i = 0; i < 2; ++i)
#pragma unroll
      for (int j = 0; j < 4; ++j)
        acc[i][j] = __builtin_amdgcn_mfma_f32_16x16x32_bf16(fa[i], fb[j], acc[i][j], 0, 0, 0);
  }

  {
    const unsigned short* qr = Aq + (t >> 1) * 64 + (t & 1) * 32;
    const float* vd = vkD + (t & 1) * 32;
    float ds = 0.f;
#pragma unroll
    for (int c = 0; c < 4; ++c) {
      bf16x8 qv = *reinterpret_cast<const bf16x8*>(qr + c * 8);
#pragma unroll
      for (int j = 0; j < 8; ++j)
        ds += bf2f((unsigned short)qv[j]) * vd[c * 8 + j];
    }
    ds += __shfl_xor(ds, 1, 64);
    if ((t & 1) == 0) invden[t >> 1] = 1.0f / (ds + EPS_LIN);
  }
  __syncthreads();

#pragma unroll
  for (int i = 0; i < 2; ++i) {
#pragma unroll
    for (int r = 0; r < 4; ++r) {
      int row = wave * 32 + i * 16 + quad * 4 + r;
      float inv = invden[row];
      unsigned short* dst = attnb + ((size_t)(b * 4096 + lt + row)) * 1024 + h * 64;
#pragma unroll
      for (int j = 0; j < 4; ++j)
        dst[j * 16 + m16] = f2bf(acc[i][j][r] * inv);
    }
  }
}

// ---------------- final rmsnorm (wave-per-row, no barriers) ----------------
__global__ __launch_bounds__(256) void k_outnorm(const unsigned short* __restrict__ preb,
                                                 const float* __restrict__ gout,
                                                 float* __restrict__ out) {
  const int row = (blockIdx.x << 2) + (threadIdx.x >> 6);
  const int lane = threadIdx.x & 63;
  const unsigned short* src = preb + (size_t)row * 1024;
  float* drow = out + (size_t)row * 1024;
  float v[16];
  float ss = 0.f;
#pragma unroll
  for (int c = 0; c < 4; ++c) {
    int d = c * 256 + lane * 4;
    ushort4 u = *reinterpret_cast<const ushort4*>(src + d);
    float a0 = bf2f(u.x), a1 = bf2f(u.y), a2 = bf2f(u.z), a3 = bf2f(u.w);
    v[c * 4 + 0] = a0; v[c * 4 + 1] = a1; v[c * 4 + 2] = a2; v[c * 4 + 3] = a3;
    ss += a0 * a0 + a1 * a1 + a2 * a2 + a3 * a3;
  }
#pragma unroll
  for (int off = 1; off < 64; off <<= 1) ss += __shfl_xor(ss, off, 64);
  const float sc = rsqrtf(ss * (1.0f / 1024.0f) + RMS_EPS);
#pragma unroll
  for (int c = 0; c < 4; ++c) {
    int d = c * 256 + lane * 4;
    float4 o = { v[c * 4 + 0] * sc * gout[d], v[c * 4 + 1] * sc * gout[d + 1],
                 v[c * 4 + 2] * sc * gout[d + 2], v[c * 4 + 3] * sc * gout[d + 3] };
    *reinterpret_cast<float4*>(drow + d) = o;
  }
}

// ---------------- workspace layout (bytes) ----------------
#define OFF_XB     0ull
#define OFF_WQKVB  33554432ull
#define OFF_WOUTB  39845888ull
#define OFF_QB     41943040ull
#define OFF_KB     75497472ull
#define OFF_VB     109051904ull
#define OFF_QFB    142606336ull
#define OFF_KFB    176160768ull
#define OFF_VK     209715200ull
#define OFF_ATTNB  210780160ull
#define OFF_COST   244334592ull
#define OFF_SINT   244858880ull
#define WS_NEEDED  245383168ull
// preb (bf16, 32MB) aliases OFF_QB (qb dead by then)
// vkpart (f32, 17MB) aliases OFF_ATTNB (consumed by k_vkred before k_res writes attnb)

extern "C" void kernel_launch(void* const* d_in, const int* in_sizes, int n_in,
                              void* d_out, int out_size, void* d_ws, size_t ws_size,
                              hipStream_t stream) {
  const float* x    = (const float*)d_in[0];
  const float* Wqkv = (const float*)d_in[1];
  const float* bqkv = (const float*)d_in[2];
  const float* gq   = (const float*)d_in[3];
  const float* gk   = (const float*)d_in[4];
  const float* Wout = (const float*)d_in[5];
  const float* bout = (const float*)d_in[6];
  const float* gout = (const float*)d_in[7];

  if (ws_size < WS_NEEDED) return;

  char* ws = (char*)d_ws;
  unsigned short* xb    = (unsigned short*)(ws + OFF_XB);
  unsigned short* wqkvb = (unsigned short*)(ws + OFF_WQKVB);
  unsigned short* woutb = (unsigned short*)(ws + OFF_WOUTB);
  unsigned short* qb    = (unsigned short*)(ws + OFF_QB);
  unsigned short* kb    = (unsigned short*)(ws + OFF_KB);
  unsigned short* vb    = (unsigned short*)(ws + OFF_VB);
  unsigned short* qfb   = (unsigned short*)(ws + OFF_QFB);
  unsigned short* kfb   = (unsigned short*)(ws + OFF_KFB);
  float*          vkbuf = (float*)(ws + OFF_VK);
  unsigned short* attnb = (unsigned short*)(ws + OFF_ATTNB);
  float*          cosT  = (float*)(ws + OFF_COST);
  float*          sinT  = (float*)(ws + OFF_SINT);
  unsigned short* preb  = (unsigned short*)(ws + OFF_QB);   // alias
  float*          vkpart = (float*)(ws + OFF_ATTNB);        // alias

  // fused init: conversions + rope table + vkbuf zero (1 launch)
  k_init<<<21252, 256, 0, stream>>>(x, Wqkv, Wout, xb, wqkvb, woutb, cosT, sinT, vkbuf);

  // QKV gemm: M=16384 N=3072 K=1024
  k_gemm_bt<<<128 * 24, 256, 0, stream>>>(xb, wqkvb, bqkv, 16384, 3072, 1024, 0,
                                          qb, kb, vb, nullptr);
  k_qknorm<<<8192, 256, 0, stream>>>(qb, kb, gq, gk, cosT, sinT, qfb, kfb);

  // R8: MFMA vk (transposed-LDS, plain ds_read_b128), partials + reduce
  k_vk<<<1024, 256, 0, stream>>>(vb, kfb, vkpart);
  k_vkred<<<260, 256, 0, stream>>>(vkpart, vkbuf);

  k_res<<<2048, 256, 0, stream>>>(qfb, vkbuf, attnb);

  // out gemm: M=16384 N=1024 K=1024 -> preb (bf16, aliases qb region)
  k_gemm_bt<<<128 * 8, 256, 0, stream>>>(attnb, woutb, bout, 16384, 1024, 1024, 1,
                                         nullptr, nullptr, nullptr, preb);
  k_outnorm<<<4096, 256, 0, stream>>>(preb, gout, (float*)d_out);
}